// Round 1
// baseline (417.598 us; speedup 1.0000x reference)
//
#include <hip/hip_runtime.h>
#include <hip/hip_bf16.h>
#include <math.h>

// Problem constants (fixed by the reference file).
constexpr int N = 100000;     // nodes
constexpr int E = 1000000;    // edges
constexpr int D = 64;         // feature dim

// ---------------------------------------------------------------------------
// Kernel A: fused dual GEMM.
//   h        = feat @ Wm + bm           -> ws (needed by edge scatter)
//   out_pre  = a * (feat @ Wn + bn)     -> d_out (partial; kernel D adds rest)
// Wn, Wm staged in LDS (32 KB). 16 rows/block, 256 threads.
// ---------------------------------------------------------------------------
__global__ __launch_bounds__(256) void node_gemm(
    const float* __restrict__ feat,
    const float* __restrict__ Wn, const float* __restrict__ bn,
    const float* __restrict__ Wm, const float* __restrict__ bm,
    const float* __restrict__ alpha,
    float* __restrict__ h, float* __restrict__ out_pre) {
  __shared__ float sWn[D * D];
  __shared__ float sWm[D * D];
  __shared__ float sF[16 * D];

  const int t = threadIdx.x;

  // Load W matrices as float4 (4096 floats = 1024 float4 each; 4 per thread).
  {
    const float4* Wn4 = reinterpret_cast<const float4*>(Wn);
    const float4* Wm4 = reinterpret_cast<const float4*>(Wm);
    float4* sWn4 = reinterpret_cast<float4*>(sWn);
    float4* sWm4 = reinterpret_cast<float4*>(sWm);
#pragma unroll
    for (int i = 0; i < 4; ++i) {
      sWn4[t + i * 256] = Wn4[t + i * 256];
      sWm4[t + i * 256] = Wm4[t + i * 256];
    }
  }
  // Load feat tile (16 rows x 64): 1024 floats = 256 float4, 1 per thread.
  const int row0 = blockIdx.x * 16;
  {
    float4* sF4 = reinterpret_cast<float4*>(sF);
    const int r = t >> 4;          // 0..15
    const int c4 = t & 15;         // float4 column group
    const int gr = row0 + r;
    float4 v = make_float4(0.f, 0.f, 0.f, 0.f);
    if (gr < N) v = reinterpret_cast<const float4*>(feat)[gr * 16 + c4];
    sF4[r * 16 + c4] = v;
  }
  __syncthreads();

  const float a = 1.f / (1.f + __expf(-alpha[0]));

  const int d = t & 63;
  const int rg = t >> 6;  // wave id 0..3 -> rows rg*4 .. rg*4+3
  float accN[4] = {0.f, 0.f, 0.f, 0.f};
  float accM[4] = {0.f, 0.f, 0.f, 0.f};
#pragma unroll 8
  for (int k = 0; k < D; ++k) {
    const float wn = sWn[k * D + d];
    const float wm = sWm[k * D + d];
#pragma unroll
    for (int j = 0; j < 4; ++j) {
      const float f = sF[(rg * 4 + j) * D + k];  // wave-uniform -> LDS broadcast
      accN[j] = fmaf(f, wn, accN[j]);
      accM[j] = fmaf(f, wm, accM[j]);
    }
  }

  const float bnd = bn[d];
  const float bmd = bm[d];
#pragma unroll
  for (int j = 0; j < 4; ++j) {
    const int gr = row0 + rg * 4 + j;
    if (gr < N) {
      h[gr * D + d] = accM[j] + bmd;
      out_pre[gr * D + d] = a * (accN[j] + bnd);
    }
  }
}

// ---------------------------------------------------------------------------
// Kernel C: edge scatter. One wave per edge, lane = feature dim.
//   agg[dst] += attn * h[src];  has_cn[dst] = 1
// ---------------------------------------------------------------------------
__global__ __launch_bounds__(256) void edge_scatter(
    const int* __restrict__ src, const int* __restrict__ dst,
    const float* __restrict__ attn, const float* __restrict__ h,
    float* __restrict__ agg, int* __restrict__ has_cn) {
  const int e = blockIdx.x * 4 + (threadIdx.x >> 6);
  if (e >= E) return;
  const int d = threadIdx.x & 63;
  const int s = src[e];
  const int v = dst[e];
  const float a = attn[e];
  if (d == 0) has_cn[v] = 1;  // idempotent store
  atomicAdd(&agg[v * D + d], a * h[s * D + d]);
}

// ---------------------------------------------------------------------------
// Kernel D: combine + per-column partial stats.
//   val = out_pre + (1-a) * (has_cn ? agg : h); write back to out_pre;
//   accumulate column sum / sumsq into sums[0..63] / sums[64..127].
// 64 rows/block, 256 threads (wave rg handles rows rg*16..rg*16+15).
// ---------------------------------------------------------------------------
__global__ __launch_bounds__(256) void combine_stats(
    const float* __restrict__ h, const float* __restrict__ agg,
    const int* __restrict__ has_cn, const float* __restrict__ alpha,
    float* __restrict__ out_pre, float* __restrict__ sums) {
  const int t = threadIdx.x;
  const int d = t & 63;
  const int rg = t >> 6;
  const float a = 1.f / (1.f + __expf(-alpha[0]));
  const float oma = 1.f - a;
  const int row0 = blockIdx.x * 64;

  float psum = 0.f, psq = 0.f;
#pragma unroll 4
  for (int j = 0; j < 16; ++j) {
    const int r = row0 + rg * 16 + j;
    if (r < N) {
      const float cn = has_cn[r] ? agg[r * D + d] : h[r * D + d];
      const float v = out_pre[r * D + d] + oma * cn;
      out_pre[r * D + d] = v;
      psum += v;
      psq = fmaf(v, v, psq);
    }
  }

  __shared__ float sS[4][D];
  __shared__ float sQ[4][D];
  sS[rg][d] = psum;
  sQ[rg][d] = psq;
  __syncthreads();
  if (t < D) {
    const float s = sS[0][t] + sS[1][t] + sS[2][t] + sS[3][t];
    const float q = sQ[0][t] + sQ[1][t] + sQ[2][t] + sQ[3][t];
    atomicAdd(&sums[t], s);
    atomicAdd(&sums[D + t], q);
  }
}

// ---------------------------------------------------------------------------
// Kernel E: finalize stats into fused scale/shift.
//   scale[d] = gamma[d] / (sqrt(var_unb[d]) + eps)
//   shift[d] = beta[d] - mean[d] * scale[d]
// ---------------------------------------------------------------------------
__global__ void finalize_stats(const float* __restrict__ sums,
                               const float* __restrict__ gamma,
                               const float* __restrict__ beta,
                               float* __restrict__ norm) {
  const int d = threadIdx.x;
  if (d < D) {
    const float mean = sums[d] * (1.f / (float)N);
    const float var = (sums[D + d] - (float)N * mean * mean) / (float)(N - 1);
    const float rstd = 1.f / (sqrtf(var) + 1e-8f);
    const float sc = gamma[d] * rstd;
    norm[d] = sc;
    norm[D + d] = beta[d] - mean * sc;
  }
}

// ---------------------------------------------------------------------------
// Kernel F: in-place normalize + ReLU on d_out, float4-vectorized.
// ---------------------------------------------------------------------------
__global__ __launch_bounds__(256) void norm_relu(float* __restrict__ out,
                                                 const float* __restrict__ norm) {
  const float4* sc4 = reinterpret_cast<const float4*>(norm);
  const float4* sh4 = reinterpret_cast<const float4*>(norm + D);
  float4* out4 = reinterpret_cast<float4*>(out);
  const int total4 = N * D / 4;
  for (int i = blockIdx.x * blockDim.x + threadIdx.x; i < total4;
       i += gridDim.x * blockDim.x) {
    float4 v = out4[i];
    const int c = i & 15;  // float4 column group within row
    const float4 s = sc4[c];
    const float4 b = sh4[c];
    v.x = fmaxf(fmaf(v.x, s.x, b.x), 0.f);
    v.y = fmaxf(fmaf(v.y, s.y, b.y), 0.f);
    v.z = fmaxf(fmaf(v.z, s.z, b.z), 0.f);
    v.w = fmaxf(fmaf(v.w, s.w, b.w), 0.f);
    out4[i] = v;
  }
}

extern "C" void kernel_launch(void* const* d_in, const int* in_sizes, int n_in,
                              void* d_out, int out_size, void* d_ws, size_t ws_size,
                              hipStream_t stream) {
  const float* feat  = (const float*)d_in[0];
  const int*   src   = (const int*)d_in[1];
  const int*   dst   = (const int*)d_in[2];
  const float* attn  = (const float*)d_in[3];
  const float* Wn    = (const float*)d_in[4];
  const float* bn    = (const float*)d_in[5];
  const float* Wm    = (const float*)d_in[6];
  const float* bm    = (const float*)d_in[7];
  const float* alpha = (const float*)d_in[8];
  const float* gamma = (const float*)d_in[9];
  const float* beta  = (const float*)d_in[10];

  float* out = (float*)d_out;

  // Workspace layout (floats):
  //   h      [N*D]
  //   agg    [N*D]
  //   flags  [N]   (int)
  //   sums   [128]
  //   norm   [128]
  float* ws = (float*)d_ws;
  float* h      = ws;
  float* agg    = ws + (size_t)N * D;
  int*   flags  = (int*)(ws + (size_t)2 * N * D);
  float* sums   = ws + (size_t)2 * N * D + N;
  float* norm   = sums + 128;

  // Zero the accumulators (ws is poisoned to 0xAA before every call).
  hipMemsetAsync(agg, 0, (size_t)N * D * sizeof(float), stream);
  hipMemsetAsync(flags, 0, (size_t)N * sizeof(int), stream);
  hipMemsetAsync(sums, 0, 128 * sizeof(float), stream);

  // A: dual GEMM
  node_gemm<<<(N + 15) / 16, 256, 0, stream>>>(feat, Wn, bn, Wm, bm, alpha, h, out);
  // C: edge scatter (E/4 blocks, 4 edges per block)
  edge_scatter<<<E / 4, 256, 0, stream>>>(src, dst, attn, h, agg, flags);
  // D: combine + column stats
  combine_stats<<<(N + 63) / 64, 256, 0, stream>>>(h, agg, flags, alpha, out, sums);
  // E: finalize
  finalize_stats<<<1, 64, 0, stream>>>(sums, gamma, beta, norm);
  // F: normalize + relu
  norm_relu<<<2048, 256, 0, stream>>>(out, norm);
}

// Round 3
// 384.446 us; speedup vs baseline: 1.0862x; 1.0862x over previous
//
#include <hip/hip_runtime.h>
#include <hip/hip_bf16.h>
#include <math.h>

// Problem constants (fixed by the reference file).
constexpr int N = 100000;     // nodes
constexpr int E = 1000000;    // edges
constexpr int D = 64;         // feature dim

// ---------------------------------------------------------------------------
// Kernel A: fused dual GEMM, 64 rows/block.
//   h        = feat @ Wm + bm           -> ws (needed by gather)
//   out_pre  = a * (feat @ Wn + bn)     -> d_out (partial; gather adds rest)
// Wn, Wm staged in LDS (32 KB) + 16 KB feat tile. 256 threads.
// ---------------------------------------------------------------------------
__global__ __launch_bounds__(256) void node_gemm(
    const float* __restrict__ feat,
    const float* __restrict__ Wn, const float* __restrict__ bn,
    const float* __restrict__ Wm, const float* __restrict__ bm,
    const float* __restrict__ alpha,
    float* __restrict__ h, float* __restrict__ out_pre) {
  __shared__ float sWn[D * D];
  __shared__ float sWm[D * D];
  __shared__ float sF[64 * D];

  const int t = threadIdx.x;

  {
    const float4* Wn4 = reinterpret_cast<const float4*>(Wn);
    const float4* Wm4 = reinterpret_cast<const float4*>(Wm);
    float4* sWn4 = reinterpret_cast<float4*>(sWn);
    float4* sWm4 = reinterpret_cast<float4*>(sWm);
#pragma unroll
    for (int i = 0; i < 4; ++i) {
      sWn4[t + i * 256] = Wn4[t + i * 256];
      sWm4[t + i * 256] = Wm4[t + i * 256];
    }
  }
  const int row0 = blockIdx.x * 64;
  {
    float4* sF4 = reinterpret_cast<float4*>(sF);
    const float4* feat4 = reinterpret_cast<const float4*>(feat);
#pragma unroll
    for (int i = 0; i < 4; ++i) {
      const int idx = t + i * 256;   // 0..1023
      const int r = idx >> 4;        // tile row 0..63
      const int c4 = idx & 15;       // float4 column group
      const int gr = row0 + r;
      float4 v = make_float4(0.f, 0.f, 0.f, 0.f);
      if (gr < N) v = feat4[gr * 16 + c4];
      sF4[idx] = v;
    }
  }
  __syncthreads();

  const float a = 1.f / (1.f + __expf(-alpha[0]));
  const int d = t & 63;
  const int rg = t >> 6;  // wave id -> rows rg*16 .. rg*16+15

  float accN[16], accM[16];
#pragma unroll
  for (int j = 0; j < 16; ++j) { accN[j] = 0.f; accM[j] = 0.f; }

  for (int k4 = 0; k4 < 16; ++k4) {
    float wn[4], wm[4];
#pragma unroll
    for (int q = 0; q < 4; ++q) {
      wn[q] = sWn[(k4 * 4 + q) * D + d];   // lanes consecutive -> 2-way (free)
      wm[q] = sWm[(k4 * 4 + q) * D + d];
    }
#pragma unroll
    for (int j = 0; j < 16; ++j) {
      // wave-uniform address -> LDS broadcast, conflict-free
      const float4 f = *reinterpret_cast<const float4*>(&sF[(rg * 16 + j) * D + k4 * 4]);
      accN[j] = fmaf(f.x, wn[0], accN[j]);
      accN[j] = fmaf(f.y, wn[1], accN[j]);
      accN[j] = fmaf(f.z, wn[2], accN[j]);
      accN[j] = fmaf(f.w, wn[3], accN[j]);
      accM[j] = fmaf(f.x, wm[0], accM[j]);
      accM[j] = fmaf(f.y, wm[1], accM[j]);
      accM[j] = fmaf(f.z, wm[2], accM[j]);
      accM[j] = fmaf(f.w, wm[3], accM[j]);
    }
  }

  const float bnd = bn[d];
  const float bmd = bm[d];
#pragma unroll
  for (int j = 0; j < 16; ++j) {
    const int gr = row0 + rg * 16 + j;
    if (gr < N) {
      h[(size_t)gr * D + d] = accM[j] + bmd;
      out_pre[(size_t)gr * D + d] = a * (accN[j] + bnd);
    }
  }
}

// ---------------------------------------------------------------------------
// CSR build step 1: in-degree histogram (1M int atomics, L2-resident counters)
// ---------------------------------------------------------------------------
__global__ __launch_bounds__(256) void edge_hist(const int* __restrict__ dst,
                                                 int* __restrict__ cnt) {
  const int e = blockIdx.x * 256 + threadIdx.x;
  if (e < E) atomicAdd(&cnt[dst[e]], 1);
}

// ---------------------------------------------------------------------------
// CSR build step 2: per-1024-block sums of cnt.
// ---------------------------------------------------------------------------
__global__ __launch_bounds__(1024) void scan_bsum(const int* __restrict__ cnt,
                                                  int* __restrict__ bsum) {
  const int i = blockIdx.x * 1024 + threadIdx.x;
  int c = (i < N) ? cnt[i] : 0;
#pragma unroll
  for (int off = 32; off; off >>= 1) c += __shfl_down(c, off, 64);
  __shared__ int wsum[16];
  if ((threadIdx.x & 63) == 0) wsum[threadIdx.x >> 6] = c;
  __syncthreads();
  if (threadIdx.x < 16) {
    int v = wsum[threadIdx.x];
#pragma unroll
    for (int off = 8; off; off >>= 1) v += __shfl_down(v, off, 16);
    if (threadIdx.x == 0) bsum[blockIdx.x] = v;
  }
}

// ---------------------------------------------------------------------------
// CSR build step 3: block-local Hillis-Steele scan + serial base from bsum,
// writes exclusive rowptr and a mutable cursor copy.
// ---------------------------------------------------------------------------
__global__ __launch_bounds__(1024) void scan_write(const int* __restrict__ cnt,
                                                   const int* __restrict__ bsum,
                                                   int* __restrict__ rowptr,
                                                   int* __restrict__ cursor) {
  __shared__ int s[1024];
  __shared__ int sbase;
  const int t = threadIdx.x;
  const int i = blockIdx.x * 1024 + t;
  const int c = (i < N) ? cnt[i] : 0;
  s[t] = c;
  if (t == 0) {
    int b = 0;
    for (int j = 0; j < (int)blockIdx.x; ++j) b += bsum[j];
    sbase = b;
  }
  __syncthreads();
  for (int off = 1; off < 1024; off <<= 1) {
    const int v = (t >= off) ? s[t - off] : 0;
    __syncthreads();
    s[t] += v;
    __syncthreads();
  }
  const int excl = s[t] - c + sbase;
  if (i < N) {
    rowptr[i] = excl;
    cursor[i] = excl;
  }
}

// ---------------------------------------------------------------------------
// CSR build step 4: fill packed (src, attn_bits) per dst segment. One 8B
// store per edge instead of two 4B stores.
// ---------------------------------------------------------------------------
__global__ __launch_bounds__(256) void edge_fill(const int* __restrict__ src,
                                                 const int* __restrict__ dst,
                                                 const float* __restrict__ attn,
                                                 int* __restrict__ cursor,
                                                 int2* __restrict__ csr) {
  const int e = blockIdx.x * 256 + threadIdx.x;
  if (e < E) {
    const int v = dst[e];
    const int pos = atomicAdd(&cursor[v], 1);
    csr[pos] = make_int2(src[e], __float_as_int(attn[e]));
  }
}

// ---------------------------------------------------------------------------
// Gather + combine + column stats. One wave per 8 nodes (lane = feature).
// Walk CSR segment with 2 independent FMA chains (ILP to hide L2/L3 gather
// latency), gate, combine with out_pre, write final pre-norm value once,
// accumulate column stats.
// ---------------------------------------------------------------------------
__global__ __launch_bounds__(256) void gather_combine(
    const float* __restrict__ h, const int* __restrict__ rowptr,
    const int* __restrict__ cnt, const int2* __restrict__ csr,
    const float* __restrict__ alpha,
    float* __restrict__ out_pre, float* __restrict__ sums) {
  const int t = threadIdx.x;
  const int d = t & 63;
  const int w = t >> 6;
  const float a = 1.f / (1.f + __expf(-alpha[0]));
  const float oma = 1.f - a;

  float psum = 0.f, psq = 0.f;
  const int vbase = blockIdx.x * 32 + w * 8;   // grid covers N exactly
#pragma unroll 1
  for (int j = 0; j < 8; ++j) {
    const int v = vbase + j;
    const int beg = rowptr[v];
    const int n = cnt[v];
    const int end = beg + n;
    float acc0 = 0.f, acc1 = 0.f;
    int i = beg;
    for (; i + 2 <= end; i += 2) {
      const int2 e0 = csr[i];        // wave-uniform -> cache broadcast
      const int2 e1 = csr[i + 1];
      acc0 = fmaf(__int_as_float(e0.y), h[(size_t)e0.x * D + d], acc0);
      acc1 = fmaf(__int_as_float(e1.y), h[(size_t)e1.x * D + d], acc1);
    }
    if (i < end) {
      const int2 e0 = csr[i];
      acc0 = fmaf(__int_as_float(e0.y), h[(size_t)e0.x * D + d], acc0);
    }
    const float acc = acc0 + acc1;
    const float cn = (n > 0) ? acc : h[(size_t)v * D + d];
    const float val = out_pre[(size_t)v * D + d] + oma * cn;
    out_pre[(size_t)v * D + d] = val;
    psum += val;
    psq = fmaf(val, val, psq);
  }

  __shared__ float sS[4][D];
  __shared__ float sQ[4][D];
  sS[w][d] = psum;
  sQ[w][d] = psq;
  __syncthreads();
  if (t < D) {
    const float s = sS[0][t] + sS[1][t] + sS[2][t] + sS[3][t];
    const float q = sQ[0][t] + sQ[1][t] + sQ[2][t] + sQ[3][t];
    atomicAdd(&sums[t], s);
    atomicAdd(&sums[D + t], q);
  }
}

// ---------------------------------------------------------------------------
// Finalize stats into fused scale/shift.
// ---------------------------------------------------------------------------
__global__ void finalize_stats(const float* __restrict__ sums,
                               const float* __restrict__ gamma,
                               const float* __restrict__ beta,
                               float* __restrict__ norm) {
  const int d = threadIdx.x;
  if (d < D) {
    const float mean = sums[d] * (1.f / (float)N);
    const float var = (sums[D + d] - (float)N * mean * mean) / (float)(N - 1);
    const float rstd = 1.f / (sqrtf(var) + 1e-8f);
    const float sc = gamma[d] * rstd;
    norm[d] = sc;
    norm[D + d] = beta[d] - mean * sc;
  }
}

// ---------------------------------------------------------------------------
// In-place normalize + ReLU on d_out, float4-vectorized.
// ---------------------------------------------------------------------------
__global__ __launch_bounds__(256) void norm_relu(float* __restrict__ out,
                                                 const float* __restrict__ norm) {
  const float4* sc4 = reinterpret_cast<const float4*>(norm);
  const float4* sh4 = reinterpret_cast<const float4*>(norm + D);
  float4* out4 = reinterpret_cast<float4*>(out);
  const int total4 = N * D / 4;
  for (int i = blockIdx.x * blockDim.x + threadIdx.x; i < total4;
       i += gridDim.x * blockDim.x) {
    float4 v = out4[i];
    const int c = i & 15;
    const float4 s = sc4[c];
    const float4 b = sh4[c];
    v.x = fmaxf(fmaf(v.x, s.x, b.x), 0.f);
    v.y = fmaxf(fmaf(v.y, s.y, b.y), 0.f);
    v.z = fmaxf(fmaf(v.z, s.z, b.z), 0.f);
    v.w = fmaxf(fmaf(v.w, s.w, b.w), 0.f);
    out4[i] = v;
  }
}

extern "C" void kernel_launch(void* const* d_in, const int* in_sizes, int n_in,
                              void* d_out, int out_size, void* d_ws, size_t ws_size,
                              hipStream_t stream) {
  const float* feat  = (const float*)d_in[0];
  const int*   src   = (const int*)d_in[1];
  const int*   dst   = (const int*)d_in[2];
  const float* attn  = (const float*)d_in[3];
  const float* Wn    = (const float*)d_in[4];
  const float* bn    = (const float*)d_in[5];
  const float* Wm    = (const float*)d_in[6];
  const float* bm    = (const float*)d_in[7];
  const float* alpha = (const float*)d_in[8];
  const float* gamma = (const float*)d_in[9];
  const float* beta  = (const float*)d_in[10];

  float* out = (float*)d_out;

  // Workspace layout (~34 MB, all fully written before read):
  float* ws      = (float*)d_ws;
  float* h       = ws;                           // N*D floats
  int*   cnt     = (int*)(h + (size_t)N * D);    // N
  int*   rowptr  = cnt + N;                      // N
  int*   cursor  = rowptr + N;                   // N
  int*   bsum    = cursor + N;                   // 128
  int2*  csr     = (int2*)(bsum + 128);          // E int2 (8B-aligned offset)
  float* sums    = (float*)(csr + E);            // 128
  float* norm    = sums + 128;                   // 128

  hipMemsetAsync(cnt, 0, (size_t)N * sizeof(int), stream);
  hipMemsetAsync(sums, 0, 128 * sizeof(float), stream);

  node_gemm<<<(N + 63) / 64, 256, 0, stream>>>(feat, Wn, bn, Wm, bm, alpha, h, out);
  edge_hist<<<(E + 255) / 256, 256, 0, stream>>>(dst, cnt);
  scan_bsum<<<(N + 1023) / 1024, 1024, 0, stream>>>(cnt, bsum);
  scan_write<<<(N + 1023) / 1024, 1024, 0, stream>>>(cnt, bsum, rowptr, cursor);
  edge_fill<<<(E + 255) / 256, 256, 0, stream>>>(src, dst, attn, cursor, csr);
  gather_combine<<<N / 32, 256, 0, stream>>>(h, rowptr, cnt, csr, alpha, out, sums);
  finalize_stats<<<1, 64, 0, stream>>>(sums, gamma, beta, norm);
  norm_relu<<<2048, 256, 0, stream>>>(out, norm);
}

// Round 7
// 348.828 us; speedup vs baseline: 1.1971x; 1.1021x over previous
//
#include <hip/hip_runtime.h>
#include <hip/hip_bf16.h>
#include <math.h>

// Problem constants (fixed by the reference file).
constexpr int N = 100000;     // nodes
constexpr int E = 1000000;    // edges
constexpr int D = 64;         // feature dim

__device__ __forceinline__ ushort f2bf(float x) {  // round-to-nearest-even bf16
  const unsigned u = __float_as_uint(x);
  return (ushort)((u + 0x7FFFu + ((u >> 16) & 1u)) >> 16);
}
__device__ __forceinline__ float bf2f(ushort u) {
  return __uint_as_float(((unsigned)u) << 16);
}

// ---------------------------------------------------------------------------
// Kernel 1: fused dual GEMM (+ in-degree histogram in the tail).
//   h2      = bf16(feat @ Wm + bm)      -> ws (gather reads 128B rows)
//   out_pre = a * (feat @ Wn + bn)      -> d_out (gather adds the rest)
// 64 rows/block, Wn/Wm + feat tile in LDS. After the GEMM each block
// grid-strides a slice of dst[] doing the histogram atomics.
// ---------------------------------------------------------------------------
__global__ __launch_bounds__(256) void node_gemm_hist(
    const float* __restrict__ feat,
    const float* __restrict__ Wn, const float* __restrict__ bn,
    const float* __restrict__ Wm, const float* __restrict__ bm,
    const float* __restrict__ alpha, const int* __restrict__ dst,
    ushort* __restrict__ h2, float* __restrict__ out_pre,
    int* __restrict__ cnt) {
  __shared__ float sWn[D * D];
  __shared__ float sWm[D * D];
  __shared__ float sF[64 * D];

  const int t = threadIdx.x;

  {
    const float4* Wn4 = reinterpret_cast<const float4*>(Wn);
    const float4* Wm4 = reinterpret_cast<const float4*>(Wm);
    float4* sWn4 = reinterpret_cast<float4*>(sWn);
    float4* sWm4 = reinterpret_cast<float4*>(sWm);
#pragma unroll
    for (int i = 0; i < 4; ++i) {
      sWn4[t + i * 256] = Wn4[t + i * 256];
      sWm4[t + i * 256] = Wm4[t + i * 256];
    }
  }
  const int row0 = blockIdx.x * 64;
  {
    float4* sF4 = reinterpret_cast<float4*>(sF);
    const float4* feat4 = reinterpret_cast<const float4*>(feat);
#pragma unroll
    for (int i = 0; i < 4; ++i) {
      const int idx = t + i * 256;   // 0..1023
      const int r = idx >> 4;        // tile row 0..63
      const int c4 = idx & 15;       // float4 column group
      const int gr = row0 + r;
      float4 v = make_float4(0.f, 0.f, 0.f, 0.f);
      if (gr < N) v = feat4[gr * 16 + c4];
      sF4[idx] = v;
    }
  }
  __syncthreads();

  const float a = 1.f / (1.f + __expf(-alpha[0]));
  const int d = t & 63;
  const int rg = t >> 6;  // wave id -> rows rg*16 .. rg*16+15

  float accN[16], accM[16];
#pragma unroll
  for (int j = 0; j < 16; ++j) { accN[j] = 0.f; accM[j] = 0.f; }

  for (int k4 = 0; k4 < 16; ++k4) {
    float wn[4], wm[4];
#pragma unroll
    for (int q = 0; q < 4; ++q) {
      wn[q] = sWn[(k4 * 4 + q) * D + d];
      wm[q] = sWm[(k4 * 4 + q) * D + d];
    }
#pragma unroll
    for (int j = 0; j < 16; ++j) {
      const float4 f = *reinterpret_cast<const float4*>(&sF[(rg * 16 + j) * D + k4 * 4]);
      accN[j] = fmaf(f.x, wn[0], accN[j]);
      accN[j] = fmaf(f.y, wn[1], accN[j]);
      accN[j] = fmaf(f.z, wn[2], accN[j]);
      accN[j] = fmaf(f.w, wn[3], accN[j]);
      accM[j] = fmaf(f.x, wm[0], accM[j]);
      accM[j] = fmaf(f.y, wm[1], accM[j]);
      accM[j] = fmaf(f.z, wm[2], accM[j]);
      accM[j] = fmaf(f.w, wm[3], accM[j]);
    }
  }

  const float bnd = bn[d];
  const float bmd = bm[d];
#pragma unroll
  for (int j = 0; j < 16; ++j) {
    const int gr = row0 + rg * 16 + j;
    if (gr < N) {
      h2[(size_t)gr * D + d] = f2bf(accM[j] + bmd);
      out_pre[(size_t)gr * D + d] = a * (accN[j] + bnd);
    }
  }

  // --- fused histogram tail ---
  const int stride = gridDim.x * 256;
  for (int e = blockIdx.x * 256 + t; e < E; e += stride)
    atomicAdd(&cnt[dst[e]], 1);
}

// ---------------------------------------------------------------------------
// Kernel 2: CSR row allocation WITHOUT a sorted scan. Segment order is
// irrelevant to the gather — allocate each wave's 64 nodes with one
// atomicAdd on a global cursor + an in-wave shfl scan.
// ---------------------------------------------------------------------------
__global__ __launch_bounds__(256) void alloc_rows(const int* __restrict__ cnt,
                                                  int* __restrict__ gcur,
                                                  int* __restrict__ rowptr,
                                                  int* __restrict__ cursor) {
  const int v = blockIdx.x * 256 + threadIdx.x;
  const int lane = threadIdx.x & 63;
  const int c = (v < N) ? cnt[v] : 0;
  int incl = c;
#pragma unroll
  for (int off = 1; off < 64; off <<= 1) {
    const int y = __shfl_up(incl, off, 64);
    if (lane >= off) incl += y;
  }
  int base = 0;
  if (lane == 63) base = atomicAdd(gcur, incl);
  base = __shfl(base, 63, 64);
  if (v < N) {
    const int p = base + incl - c;
    rowptr[v] = p;
    cursor[v] = p;
  }
}

// ---------------------------------------------------------------------------
// Kernel 3: fill packed (src, attn_bits) per dst segment.
// ---------------------------------------------------------------------------
__global__ __launch_bounds__(256) void edge_fill(const int* __restrict__ src,
                                                 const int* __restrict__ dst,
                                                 const float* __restrict__ attn,
                                                 int* __restrict__ cursor,
                                                 int2* __restrict__ csr) {
  const int e = blockIdx.x * 256 + threadIdx.x;
  if (e < E) {
    const int v = dst[e];
    const int pos = atomicAdd(&cursor[v], 1);
    csr[pos] = make_int2(src[e], __float_as_int(attn[e]));
  }
}

// ---------------------------------------------------------------------------
// Kernel 4: gather + combine + column stats. One wave per 8 nodes
// (lane = feature). bf16 h rows (128B) + 4 independent FMA chains to keep
// 4 gathers in flight per wave.
// ---------------------------------------------------------------------------
__global__ __launch_bounds__(256) void gather_combine(
    const ushort* __restrict__ h2, const int* __restrict__ rowptr,
    const int* __restrict__ cnt, const int2* __restrict__ csr,
    const float* __restrict__ alpha,
    float* __restrict__ out_pre, float* __restrict__ sums) {
  const int t = threadIdx.x;
  const int d = t & 63;
  const int w = t >> 6;
  const float a = 1.f / (1.f + __expf(-alpha[0]));
  const float oma = 1.f - a;

  float psum = 0.f, psq = 0.f;
  const int vbase = blockIdx.x * 32 + w * 8;   // grid covers N exactly
#pragma unroll 1
  for (int j = 0; j < 8; ++j) {
    const int v = vbase + j;
    const int beg = rowptr[v];
    const int n = cnt[v];
    const int end = beg + n;
    float acc0 = 0.f, acc1 = 0.f, acc2 = 0.f, acc3 = 0.f;
    int i = beg;
    for (; i + 4 <= end; i += 4) {
      const int2 e0 = csr[i];          // wave-uniform -> cache broadcast
      const int2 e1 = csr[i + 1];
      const int2 e2 = csr[i + 2];
      const int2 e3 = csr[i + 3];
      const float h0 = bf2f(h2[(size_t)e0.x * D + d]);
      const float h1 = bf2f(h2[(size_t)e1.x * D + d]);
      const float h2v = bf2f(h2[(size_t)e2.x * D + d]);
      const float h3 = bf2f(h2[(size_t)e3.x * D + d]);
      acc0 = fmaf(__int_as_float(e0.y), h0, acc0);
      acc1 = fmaf(__int_as_float(e1.y), h1, acc1);
      acc2 = fmaf(__int_as_float(e2.y), h2v, acc2);
      acc3 = fmaf(__int_as_float(e3.y), h3, acc3);
    }
    for (; i < end; ++i) {
      const int2 e0 = csr[i];
      acc0 = fmaf(__int_as_float(e0.y), bf2f(h2[(size_t)e0.x * D + d]), acc0);
    }
    float cn;
    if (n > 0) {                      // wave-uniform branch
      cn = (acc0 + acc1) + (acc2 + acc3);
    } else {
      cn = bf2f(h2[(size_t)v * D + d]);
    }
    const float val = out_pre[(size_t)v * D + d] + oma * cn;
    out_pre[(size_t)v * D + d] = val;
    psum += val;
    psq = fmaf(val, val, psq);
  }

  __shared__ float sS[4][D];
  __shared__ float sQ[4][D];
  sS[w][d] = psum;
  sQ[w][d] = psq;
  __syncthreads();
  if (t < D) {
    const float s = sS[0][t] + sS[1][t] + sS[2][t] + sS[3][t];
    const float q = sQ[0][t] + sQ[1][t] + sQ[2][t] + sQ[3][t];
    atomicAdd(&sums[t], s);
    atomicAdd(&sums[D + t], q);
  }
}

// ---------------------------------------------------------------------------
// Kernel 5: normalize + ReLU, with the stats finalize inlined (each block
// derives scale/shift from sums/gamma/beta — L2-hot, negligible).
// ---------------------------------------------------------------------------
__global__ __launch_bounds__(256) void norm_relu(float* __restrict__ out,
                                                 const float* __restrict__ sums,
                                                 const float* __restrict__ gamma,
                                                 const float* __restrict__ beta) {
  __shared__ float sSc[D];
  __shared__ float sSh[D];
  const int t = threadIdx.x;
  if (t < D) {
    const float mean = sums[t] * (1.f / (float)N);
    const float var = (sums[D + t] - (float)N * mean * mean) / (float)(N - 1);
    const float rstd = 1.f / (sqrtf(var) + 1e-8f);
    const float sc = gamma[t] * rstd;
    sSc[t] = sc;
    sSh[t] = beta[t] - mean * sc;
  }
  __syncthreads();

  float4* out4 = reinterpret_cast<float4*>(out);
  const int total4 = N * D / 4;
  const int stride = gridDim.x * blockDim.x;   // multiple of 16 -> c fixed
  const int i0 = blockIdx.x * blockDim.x + t;
  const int c = i0 & 15;
  const float4 s = make_float4(sSc[c * 4], sSc[c * 4 + 1], sSc[c * 4 + 2], sSc[c * 4 + 3]);
  const float4 b = make_float4(sSh[c * 4], sSh[c * 4 + 1], sSh[c * 4 + 2], sSh[c * 4 + 3]);
  for (int i = i0; i < total4; i += stride) {
    float4 v = out4[i];
    v.x = fmaxf(fmaf(v.x, s.x, b.x), 0.f);
    v.y = fmaxf(fmaf(v.y, s.y, b.y), 0.f);
    v.z = fmaxf(fmaf(v.z, s.z, b.z), 0.f);
    v.w = fmaxf(fmaf(v.w, s.w, b.w), 0.f);
    out4[i] = v;
  }
}

extern "C" void kernel_launch(void* const* d_in, const int* in_sizes, int n_in,
                              void* d_out, int out_size, void* d_ws, size_t ws_size,
                              hipStream_t stream) {
  const float* feat  = (const float*)d_in[0];
  const int*   src   = (const int*)d_in[1];
  const int*   dst   = (const int*)d_in[2];
  const float* attn  = (const float*)d_in[3];
  const float* Wn    = (const float*)d_in[4];
  const float* bn    = (const float*)d_in[5];
  const float* Wm    = (const float*)d_in[6];
  const float* bm    = (const float*)d_in[7];
  const float* alpha = (const float*)d_in[8];
  const float* gamma = (const float*)d_in[9];
  const float* beta  = (const float*)d_in[10];

  float* out = (float*)d_out;

  // Workspace layout (~22 MB):
  //   h2[N*D] ushort | cnt[N] gcur[32] sums[128] (one memset) | rowptr[N]
  //   cursor[N] | csr[E] int2
  ushort* h2     = (ushort*)d_ws;
  int*    cnt    = (int*)(h2 + (size_t)N * D);
  int*    gcur   = cnt + N;
  float*  sums   = (float*)(gcur + 32);
  int*    rowptr = (int*)(sums + 128);
  int*    cursor = rowptr + N;
  int2*   csr    = (int2*)(cursor + N);

  hipMemsetAsync(cnt, 0, (size_t)(N + 32 + 128) * sizeof(int), stream);

  node_gemm_hist<<<(N + 63) / 64, 256, 0, stream>>>(feat, Wn, bn, Wm, bm, alpha,
                                                    dst, h2, out, cnt);
  alloc_rows<<<(N + 255) / 256, 256, 0, stream>>>(cnt, gcur, rowptr, cursor);
  edge_fill<<<(E + 255) / 256, 256, 0, stream>>>(src, dst, attn, cursor, csr);
  gather_combine<<<N / 32, 256, 0, stream>>>(h2, rowptr, cnt, csr, alpha, out, sums);
  norm_relu<<<2048, 256, 0, stream>>>(out, sums, gamma, beta);
}